// Round 6
// baseline (77.520 us; speedup 1.0000x reference)
//
#include <hip/hip_runtime.h>

typedef unsigned long long ull;

#define D_IN 512
#define NBLK 256
#define SCALE 16777216.0f
#define INV_SCALE 5.9604644775390625e-08f

#define AG __HIP_MEMORY_SCOPE_AGENT

// ws byte offsets
#define WS_TFX   0        // ull[8*512]   = 32 KB  fixed-point t, 8 copies
#define WS_CNT   32768    // ull[5]: wv_cnt, wv_done, t_cnt, rp_cnt, r_done
#define WS_WVP   33024    // float[32*512]  w_v slices
#define WS_WV    98560    // float[512]     reduced w_v
#define WS_RP    100608   // float[32*512]  r slices
#define WS_R     166144   // float[512]     reduced r
#define N_ZERO   4128     // ulls from WS_TFX through counters (+pad)

__device__ __forceinline__ void fstore_cg(float* p, float v) {
    __hip_atomic_store((unsigned*)p, __builtin_bit_cast(unsigned, v),
                       __ATOMIC_RELAXED, AG);
}
__device__ __forceinline__ float fload_cg(const float* p) {
    unsigned u = __hip_atomic_load((const unsigned*)p, __ATOMIC_RELAXED, AG);
    return __builtin_bit_cast(float, u);
}

// ---------------------------------------------------------------------------
// K0: zero protocol state (poison-proof; must run every call)
// ---------------------------------------------------------------------------
__global__ __launch_bounds__(256) void k_init(ull* __restrict__ z) {
    int i = blockIdx.x * 256 + threadIdx.x;
    for (; i < N_ZERO; i += 16 * 256) z[i] = 0ull;
}

// ---------------------------------------------------------------------------
// K1: everything else. 256 blocks x 512 threads; 32 rows/block, 4 rows/wave.
// Cross-block handoffs via agent-scope atomics (coherence point), never
// grid.sync. Deterministic: fixed-order slice reductions + commutative
// integer fixed-point atomics.
// ---------------------------------------------------------------------------
__global__ __launch_bounds__(512) void k_mega(
    const float* __restrict__ X,
    const float* __restrict__ W_Q,
    const float* __restrict__ W_K,
    const float* __restrict__ W_V,
    const float* __restrict__ head_w,
    const float* __restrict__ head_b,
    float* __restrict__ out,
    char* __restrict__ ws)
{
    ull*   t_fixed = (ull*)(ws + WS_TFX);
    ull*   cnts    = (ull*)(ws + WS_CNT);
    ull*   wv_cnt  = cnts + 0;
    ull*   wv_done = cnts + 1;
    ull*   t_cnt   = cnts + 2;
    ull*   rp_cnt  = cnts + 3;
    ull*   r_done  = cnts + 4;
    float* wvp     = (float*)(ws + WS_WVP);
    float* wv      = (float*)(ws + WS_WV);
    float* rp      = (float*)(ws + WS_RP);
    float* rv      = (float*)(ws + WS_R);

    const int b    = blockIdx.x;
    const int tid  = threadIdx.x;
    const int lane = tid & 63;
    const int wid  = tid >> 6;       // 0..7
    const int c0   = lane * 4;
    const int c1   = 256 + lane * 4;

    __shared__ float lds[8][D_IN];
    __shared__ float t_lds[D_IN];
    __shared__ float u_lds[8];
    __shared__ unsigned flag_s;

    // ---- issue this wave's 4 X rows into registers (in flight during phase 1)
    float4 xa[4], xb[4];
    const int row0 = b * 32 + wid * 4;
#pragma unroll
    for (int r = 0; r < 4; ++r) {
        const float* xr = X + (size_t)(row0 + r) * D_IN;
        xa[r] = *(const float4*)(xr + c0);
        xb[r] = *(const float4*)(xr + c1);
    }

    // ---------------- Phase 1: blocks 0..31 build w_v ----------------------
    if (b < 32) {
        float acc = 0.f;
#pragma unroll
        for (int m = 0; m < 8; ++m)
            acc += head_w[b * 8 + m] * W_V[(size_t)(b * 8 + m) * D_IN + tid];
        fstore_cg(&wvp[(size_t)b * D_IN + tid], acc);
        __syncthreads();                       // drains stores (vmcnt) for whole block
        if (tid == 0) {
            ull old = __hip_atomic_fetch_add(wv_cnt, 1ull, __ATOMIC_ACQ_REL, AG);
            flag_s = (old == 31ull) ? 1u : 0u;
        }
        __syncthreads();
        if (flag_s) {                          // designated reducer, fixed order
            float s = 0.f;
#pragma unroll 8
            for (int j = 0; j < 32; ++j) s += fload_cg(&wvp[(size_t)j * D_IN + tid]);
            fstore_cg(&wv[tid], s);
            __syncthreads();
            if (tid == 0) __hip_atomic_store(wv_done, 1ull, __ATOMIC_RELEASE, AG);
        }
    }

    // ---- all blocks: wait for w_v
    if (tid == 0) {
        while (__hip_atomic_load(wv_done, __ATOMIC_ACQUIRE, AG) == 0ull)
            __builtin_amdgcn_s_sleep(2);
    }
    __syncthreads();

    float4 wv0, wv1;
    wv0.x = fload_cg(&wv[c0+0]); wv0.y = fload_cg(&wv[c0+1]);
    wv0.z = fload_cg(&wv[c0+2]); wv0.w = fload_cg(&wv[c0+3]);
    wv1.x = fload_cg(&wv[c1+0]); wv1.y = fload_cg(&wv[c1+1]);
    wv1.z = fload_cg(&wv[c1+2]); wv1.w = fload_cg(&wv[c1+3]);

    // ---------------- Phase 2: s_i dot + rank-1 t (from registers) ---------
    float4 t0 = {0.f,0.f,0.f,0.f};
    float4 t1 = {0.f,0.f,0.f,0.f};
#pragma unroll
    for (int r = 0; r < 4; ++r) {
        float p = xa[r].x*wv0.x + xa[r].y*wv0.y + xa[r].z*wv0.z + xa[r].w*wv0.w
                + xb[r].x*wv1.x + xb[r].y*wv1.y + xb[r].z*wv1.z + xb[r].w*wv1.w;
#pragma unroll
        for (int off = 32; off >= 1; off >>= 1) p += __shfl_xor(p, off, 64);
        t0.x += p*xa[r].x; t0.y += p*xa[r].y; t0.z += p*xa[r].z; t0.w += p*xa[r].w;
        t1.x += p*xb[r].x; t1.y += p*xb[r].y; t1.z += p*xb[r].z; t1.w += p*xb[r].w;
    }
    *(float4*)(&lds[wid][c0]) = t0;
    *(float4*)(&lds[wid][c1]) = t1;
    __syncthreads();
    {
        float s = 0.f;
#pragma unroll
        for (int w = 0; w < 8; ++w) s += lds[w][tid];
        const long long v = llrintf(s * SCALE);
        ull old = __hip_atomic_fetch_add(&t_fixed[(size_t)(b & 7) * D_IN + tid],
                                         (ull)v, __ATOMIC_RELAXED, AG);
        unsigned keep = (unsigned)old ^ (unsigned)(old >> 32);
        asm volatile("" :: "v"(keep));         // RMW applied before barrier (R5 pattern)
    }
    __syncthreads();

    if (tid == 0) {
        ull old = __hip_atomic_fetch_add(t_cnt, 1ull, __ATOMIC_ACQ_REL, AG);
        flag_s = (unsigned)old;
    }
    __syncthreads();
    const unsigned arrival = flag_s;

    // ---------------- Phase 3: last-32 arrivals do u and rp slices ---------
    if (arrival >= 224u) {
        const int k = (int)arrival - 224;
        if (tid == 0) {
            while (__hip_atomic_load(t_cnt, __ATOMIC_ACQUIRE, AG) < 256ull)
                __builtin_amdgcn_s_sleep(2);
        }
        __syncthreads();

        long long acc = 0;
#pragma unroll
        for (int j = 0; j < 8; ++j)
            acc += (long long)__hip_atomic_load(&t_fixed[(size_t)j * D_IN + tid],
                                                __ATOMIC_RELAXED, AG);
        t_lds[tid] = (float)acc * INV_SCALE;
        __syncthreads();

        {   // u[e] for e = 8k + wid
            const int e = 8 * k + wid;
            const float4 ta = *(const float4*)(t_lds + c0);
            const float4 tb = *(const float4*)(t_lds + c1);
            const float4 ka = *(const float4*)(W_K + (size_t)e * D_IN + c0);
            const float4 kb = *(const float4*)(W_K + (size_t)e * D_IN + c1);
            float p = ta.x*ka.x + ta.y*ka.y + ta.z*ka.z + ta.w*ka.w
                    + tb.x*kb.x + tb.y*kb.y + tb.z*kb.z + tb.w*kb.w;
#pragma unroll
            for (int off = 32; off >= 1; off >>= 1) p += __shfl_xor(p, off, 64);
            if (lane == 0) u_lds[wid] = p;
        }
        __syncthreads();

        {   // rp[k][tid] = sum_m u[m] * W_Q[8k+m][tid]
            float racc = 0.f;
#pragma unroll
            for (int m = 0; m < 8; ++m)
                racc += u_lds[m] * W_Q[(size_t)(8 * k + m) * D_IN + tid];
            fstore_cg(&rp[(size_t)k * D_IN + tid], racc);
        }
        __syncthreads();
        if (tid == 0) {
            ull old = __hip_atomic_fetch_add(rp_cnt, 1ull, __ATOMIC_ACQ_REL, AG);
            flag_s = (old == 31ull) ? 1u : 0u;
        }
        __syncthreads();
        if (flag_s) {                          // designated r reducer, fixed order
            float s = 0.f;
#pragma unroll 8
            for (int j = 0; j < 32; ++j) s += fload_cg(&rp[(size_t)j * D_IN + tid]);
            fstore_cg(&rv[tid], s);
            __syncthreads();
            if (tid == 0) __hip_atomic_store(r_done, 1ull, __ATOMIC_RELEASE, AG);
        }
    }

    // ---------------- Phase 4: wait r; final dot from registers ------------
    if (tid == 0) {
        while (__hip_atomic_load(r_done, __ATOMIC_ACQUIRE, AG) == 0ull)
            __builtin_amdgcn_s_sleep(2);
    }
    __syncthreads();

    float4 r0, r1;
    r0.x = fload_cg(&rv[c0+0]); r0.y = fload_cg(&rv[c0+1]);
    r0.z = fload_cg(&rv[c0+2]); r0.w = fload_cg(&rv[c0+3]);
    r1.x = fload_cg(&rv[c1+0]); r1.y = fload_cg(&rv[c1+1]);
    r1.z = fload_cg(&rv[c1+2]); r1.w = fload_cg(&rv[c1+3]);
    const float bb = head_b[0];

#pragma unroll
    for (int r = 0; r < 4; ++r) {
        float p = xa[r].x*r0.x + xa[r].y*r0.y + xa[r].z*r0.z + xa[r].w*r0.w
                + xb[r].x*r1.x + xb[r].y*r1.y + xb[r].z*r1.z + xb[r].w*r1.w;
#pragma unroll
        for (int off = 32; off >= 1; off >>= 1) p += __shfl_xor(p, off, 64);
        if (lane == 0) out[row0 + r] = p + bb;
    }
}

// ---------------------------------------------------------------------------
extern "C" void kernel_launch(void* const* d_in, const int* in_sizes, int n_in,
                              void* d_out, int out_size, void* d_ws, size_t ws_size,
                              hipStream_t stream) {
    const float* X      = (const float*)d_in[0];
    const float* W_Q    = (const float*)d_in[1];
    const float* W_K    = (const float*)d_in[2];
    const float* W_V    = (const float*)d_in[3];
    const float* head_w = (const float*)d_in[4];
    const float* head_b = (const float*)d_in[5];
    float* out = (float*)d_out;
    char* ws   = (char*)d_ws;

    k_init<<<16,   256, 0, stream>>>((ull*)ws);
    k_mega<<<NBLK, 512, 0, stream>>>(X, W_Q, W_K, W_V, head_w, head_b, out, ws);
}

// Round 7
// 33.806 us; speedup vs baseline: 2.2931x; 2.2931x over previous
//
#include <hip/hip_runtime.h>

typedef unsigned long long ull;

#define D_IN 512
#define EMBED 256
#define NBLK 256
#define SCALE 16777216.0f
#define INV_SCALE 5.9604644775390625e-08f
#define AG __HIP_MEMORY_SCOPE_AGENT

// ws byte layout:
//   t_fixed @ 0      : ull[8*512] (32 KB) fixed-point t, 8 copies
//   cnts    @ 32768  : ull[8]  (t_cnt, rp_cnt, r_done)
//   wvp     @ 32832  : float[8*512]   w_v slices (8 e-chunks of 32)
//   rp      @ 49216  : float[32*512]  r slices
//   rv      @ 114752 : float[512]     reduced r
#define WS_TFX 0
#define WS_CNT 32768
#define WS_WVP 32832
#define WS_RP  49216
#define WS_RV  114752
#define N_ZERO 4104      // t_fixed (4096) + cnts (8)

// Relaxed agent-scope accessors: go to the L3 coherence point, NO buffer_inv
// (acquire) and NO L2 writeback storms (acq_rel) — the R6 failure mechanism.
__device__ __forceinline__ void fstore_cg(float* p, float v) {
    __hip_atomic_store((unsigned*)p, __builtin_bit_cast(unsigned, v),
                       __ATOMIC_RELAXED, AG);
}
__device__ __forceinline__ float fload_cg(const float* p) {
    unsigned u = __hip_atomic_load((const unsigned*)p, __ATOMIC_RELAXED, AG);
    return __builtin_bit_cast(float, u);
}
__device__ __forceinline__ ull uload_cg(const ull* p) {
    return __hip_atomic_load(p, __ATOMIC_RELAXED, AG);
}

// ---------------------------------------------------------------------------
// K0: wvp slices + zero protocol state. 8 blocks x 512 threads, no sync.
// Plain stores: kernel-end writeback makes them visible to K1 (R5-proven).
// ---------------------------------------------------------------------------
__global__ __launch_bounds__(512) void k_prep(const float* __restrict__ W_V,
                                              const float* __restrict__ head_w,
                                              float* __restrict__ wvp,
                                              ull* __restrict__ z) {
    const int j   = blockIdx.x;      // 0..7 -> e chunk [32j, 32j+32)
    const int tid = threadIdx.x;     // column
    float acc = 0.f;
    const int e0 = j * 32;
#pragma unroll 8
    for (int m = 0; m < 32; ++m)
        acc += head_w[e0 + m] * W_V[(size_t)(e0 + m) * D_IN + tid];
    wvp[(size_t)j * D_IN + tid] = acc;

    for (int i = j * 512 + tid; i < N_ZERO; i += 8 * 512) z[i] = 0ull;
}

// ---------------------------------------------------------------------------
// K1: everything else. 256 blocks x 512 threads (1 block/CU -> co-resident).
// X rows held in registers; read from HBM exactly once.
// All cross-block sync: RELAXED RMW/loads only (R5's proven protocol).
// Deterministic: fixed-order slice reductions + commutative int atomics.
// ---------------------------------------------------------------------------
__global__ __launch_bounds__(512) void k_fused2(
    const float* __restrict__ X,
    const float* __restrict__ W_Q,
    const float* __restrict__ W_K,
    const float* __restrict__ head_b,
    float* __restrict__ out,
    char* __restrict__ ws)
{
    ull*   t_fixed = (ull*)(ws + WS_TFX);
    ull*   cnts    = (ull*)(ws + WS_CNT);
    ull*   t_cnt   = cnts + 0;
    ull*   rp_cnt  = cnts + 1;
    ull*   r_done  = cnts + 2;
    float* wvp     = (float*)(ws + WS_WVP);
    float* rp      = (float*)(ws + WS_RP);
    float* rv      = (float*)(ws + WS_RV);

    const int b    = blockIdx.x;
    const int tid  = threadIdx.x;
    const int lane = tid & 63;
    const int wid  = tid >> 6;       // 0..7
    const int c0   = lane * 4;
    const int c1   = 256 + lane * 4;

    __shared__ float lds[8][D_IN];
    __shared__ float t_lds[D_IN];
    __shared__ float u_lds[8];
    __shared__ unsigned flag_s;

    // ---- issue this wave's 4 X rows into registers (HBM, exactly once)
    float4 xa[4], xb[4];
    const int row0 = b * 32 + wid * 4;
#pragma unroll
    for (int r = 0; r < 4; ++r) {
        const float* xr = X + (size_t)(row0 + r) * D_IN;
        xa[r] = *(const float4*)(xr + c0);
        xb[r] = *(const float4*)(xr + c1);
    }

    // ---- w_v: reduce the 8 prep slices (relaxed sc1 loads, fixed order)
    float4 wv0 = {0.f,0.f,0.f,0.f}, wv1 = {0.f,0.f,0.f,0.f};
#pragma unroll
    for (int j = 0; j < 8; ++j) {
        const float* s = wvp + (size_t)j * D_IN;
        wv0.x += fload_cg(s + c0 + 0); wv0.y += fload_cg(s + c0 + 1);
        wv0.z += fload_cg(s + c0 + 2); wv0.w += fload_cg(s + c0 + 3);
        wv1.x += fload_cg(s + c1 + 0); wv1.y += fload_cg(s + c1 + 1);
        wv1.z += fload_cg(s + c1 + 2); wv1.w += fload_cg(s + c1 + 3);
    }

    // ---- phase 2: s_i dot + rank-1 t (from registers)
    float4 t0 = {0.f,0.f,0.f,0.f};
    float4 t1 = {0.f,0.f,0.f,0.f};
#pragma unroll
    for (int r = 0; r < 4; ++r) {
        float p = xa[r].x*wv0.x + xa[r].y*wv0.y + xa[r].z*wv0.z + xa[r].w*wv0.w
                + xb[r].x*wv1.x + xb[r].y*wv1.y + xb[r].z*wv1.z + xb[r].w*wv1.w;
#pragma unroll
        for (int off = 32; off >= 1; off >>= 1) p += __shfl_xor(p, off, 64);
        t0.x += p*xa[r].x; t0.y += p*xa[r].y; t0.z += p*xa[r].z; t0.w += p*xa[r].w;
        t1.x += p*xb[r].x; t1.y += p*xb[r].y; t1.z += p*xb[r].z; t1.w += p*xb[r].w;
    }
    *(float4*)(&lds[wid][c0]) = t0;
    *(float4*)(&lds[wid][c1]) = t1;
    __syncthreads();
    {
        float s = 0.f;
#pragma unroll
        for (int w = 0; w < 8; ++w) s += lds[w][tid];
        const long long v = llrintf(s * SCALE);
        ull old = atomicAdd(&t_fixed[(size_t)(b & 7) * D_IN + tid], (ull)v);
        unsigned keep = (unsigned)old ^ (unsigned)(old >> 32);
        asm volatile("" :: "v"(keep));   // RMW applied before barrier (R5 pattern)
    }
    __syncthreads();

    if (tid == 0) flag_s = (unsigned)atomicAdd(t_cnt, 1ull);
    __syncthreads();
    const unsigned arrival = flag_s;

    // ---- phase 3: last-32 arrivals compute u and rp slices (R5-verbatim)
    if (arrival >= 224u) {
        const int k = (int)arrival - 224;
        if (tid == 0) {
            while (atomicAdd(t_cnt, 0ull) < 256ull) __builtin_amdgcn_s_sleep(8);
        }
        __syncthreads();

        long long acc = 0;
#pragma unroll
        for (int j = 0; j < 8; ++j)
            acc += (long long)atomicAdd(&t_fixed[(size_t)j * D_IN + tid], 0ull);
        t_lds[tid] = (float)acc * INV_SCALE;
        __syncthreads();

        {   // u[e] for e = 8k + wid
            const int e = 8 * k + wid;
            const float4 ta = *(const float4*)(t_lds + c0);
            const float4 tb = *(const float4*)(t_lds + c1);
            const float4 ka = *(const float4*)(W_K + (size_t)e * D_IN + c0);
            const float4 kb = *(const float4*)(W_K + (size_t)e * D_IN + c1);
            float p = ta.x*ka.x + ta.y*ka.y + ta.z*ka.z + ta.w*ka.w
                    + tb.x*kb.x + tb.y*kb.y + tb.z*kb.z + tb.w*kb.w;
#pragma unroll
            for (int off = 32; off >= 1; off >>= 1) p += __shfl_xor(p, off, 64);
            if (lane == 0) u_lds[wid] = p;
        }
        __syncthreads();

        {   // rp[k][tid] = sum_m u[m] * W_Q[8k+m][tid]
            float racc = 0.f;
#pragma unroll
            for (int m = 0; m < 8; ++m)
                racc += u_lds[m] * W_Q[(size_t)(8 * k + m) * D_IN + tid];
            fstore_cg(&rp[(size_t)k * D_IN + tid], racc);
        }
        __syncthreads();                 // drains vmcnt -> rp at L3
        if (tid == 0) flag_s = ((unsigned)atomicAdd(rp_cnt, 1ull) == 31u) ? 1u : 0u;
        __syncthreads();

        if (flag_s) {                    // designated r reducer, fixed order
            float s = 0.f;
#pragma unroll 8
            for (int j = 0; j < 32; ++j) s += fload_cg(&rp[(size_t)j * D_IN + tid]);
            fstore_cg(&rv[tid], s);
            __syncthreads();             // drains vmcnt -> rv at L3
            if (tid == 0) atomicAdd(r_done, 1ull);
        }
    }

    // ---- phase 4: relaxed-poll r_done; final dot from registers
    if (tid == 0) {
        while (uload_cg(r_done) == 0ull) __builtin_amdgcn_s_sleep(4);
    }
    __syncthreads();

    float4 r0, r1;
    r0.x = fload_cg(&rv[c0+0]); r0.y = fload_cg(&rv[c0+1]);
    r0.z = fload_cg(&rv[c0+2]); r0.w = fload_cg(&rv[c0+3]);
    r1.x = fload_cg(&rv[c1+0]); r1.y = fload_cg(&rv[c1+1]);
    r1.z = fload_cg(&rv[c1+2]); r1.w = fload_cg(&rv[c1+3]);
    const float bb = head_b[0];

#pragma unroll
    for (int r = 0; r < 4; ++r) {
        float p = xa[r].x*r0.x + xa[r].y*r0.y + xa[r].z*r0.z + xa[r].w*r0.w
                + xb[r].x*r1.x + xb[r].y*r1.y + xb[r].z*r1.z + xb[r].w*r1.w;
#pragma unroll
        for (int off = 32; off >= 1; off >>= 1) p += __shfl_xor(p, off, 64);
        if (lane == 0) out[row0 + r] = p + bb;
    }
}

// ---------------------------------------------------------------------------
extern "C" void kernel_launch(void* const* d_in, const int* in_sizes, int n_in,
                              void* d_out, int out_size, void* d_ws, size_t ws_size,
                              hipStream_t stream) {
    const float* X      = (const float*)d_in[0];
    const float* W_Q    = (const float*)d_in[1];
    const float* W_K    = (const float*)d_in[2];
    const float* W_V    = (const float*)d_in[3];
    const float* head_w = (const float*)d_in[4];
    const float* head_b = (const float*)d_in[5];
    float* out = (float*)d_out;
    char* ws   = (char*)d_ws;

    float* wvp = (float*)(ws + WS_WVP);

    k_prep  <<<8,    512, 0, stream>>>(W_V, head_w, wvp, (ull*)ws);
    k_fused2<<<NBLK, 512, 0, stream>>>(X, W_Q, W_K, head_b, out, ws);
}

// Round 8
// 27.133 us; speedup vs baseline: 2.8570x; 1.2459x over previous
//
#include <hip/hip_runtime.h>

typedef unsigned long long ull;

#define D_IN 512
#define EMBED 256
#define NBLK 256
#define SCALE 16777216.0f
#define INV_SCALE 5.9604644775390625e-08f
#define AG __HIP_MEMORY_SCOPE_AGENT

// ws byte layout:
//   t_fixed @ 0      : ull[8*512] (32 KB) fixed-point t, 8 copies
//   cnts    @ 32768  : ull[8]  (t_cnt, rp_cnt, r_done)
//   wvp     @ 32832  : float[8*512]   w_v slices (8 e-chunks of 32)
//   rp      @ 49216  : float[32*512]  r slices
//   rv      @ 114752 : float[512]     reduced r
#define WS_TFX 0
#define WS_CNT 32768
#define WS_WVP 32832
#define WS_RP  49216
#define WS_RV  114752
#define N_ZERO 4104      // t_fixed (4096) + cnts (8)

// Relaxed agent-scope accessors (coherence-point access, no buffer_inv).
// Used ONLY for low-volume protocol data — never for broadcast fan-out
// (R7 lesson: 2M scalar atomic loads to hot ranges cost ~10 us).
__device__ __forceinline__ void fstore_cg(float* p, float v) {
    __hip_atomic_store((unsigned*)p, __builtin_bit_cast(unsigned, v),
                       __ATOMIC_RELAXED, AG);
}
__device__ __forceinline__ float fload_cg(const float* p) {
    unsigned u = __hip_atomic_load((const unsigned*)p, __ATOMIC_RELAXED, AG);
    return __builtin_bit_cast(float, u);
}
__device__ __forceinline__ ull uload_cg(const ull* p) {
    return __hip_atomic_load(p, __ATOMIC_RELAXED, AG);
}

// ---------------------------------------------------------------------------
// K0: wvp slices + zero protocol state. 8 blocks x 512 threads.
// Plain stores: kernel-boundary writeback/invalidate makes them visible to
// K1's PLAIN loads (stream-ordered dispatch; the R2-R5 kernels relied on it).
// ---------------------------------------------------------------------------
__global__ __launch_bounds__(512) void k_prep(const float* __restrict__ W_V,
                                              const float* __restrict__ head_w,
                                              float* __restrict__ wvp,
                                              ull* __restrict__ z) {
    const int j   = blockIdx.x;      // 0..7 -> e chunk [32j, 32j+32)
    const int tid = threadIdx.x;     // column
    float acc = 0.f;
    const int e0 = j * 32;
#pragma unroll 8
    for (int m = 0; m < 32; ++m)
        acc += head_w[e0 + m] * W_V[(size_t)(e0 + m) * D_IN + tid];
    wvp[(size_t)j * D_IN + tid] = acc;

    for (int i = j * 512 + tid; i < N_ZERO; i += 8 * 512) z[i] = 0ull;
}

// ---------------------------------------------------------------------------
// K1: 256 blocks x 512 threads (1 block/CU -> co-resident by capacity).
// X rows held in registers; HBM-read exactly once.
// Cross-block handoff: relaxed atomics only; broadcasts staged via LDS.
// Deterministic: fixed-order slice reductions + commutative int atomics.
// ---------------------------------------------------------------------------
__global__ __launch_bounds__(512) void k_fused2(
    const float* __restrict__ X,
    const float* __restrict__ W_Q,
    const float* __restrict__ W_K,
    const float* __restrict__ head_b,
    float* __restrict__ out,
    char* __restrict__ ws)
{
    ull*   t_fixed = (ull*)(ws + WS_TFX);
    ull*   cnts    = (ull*)(ws + WS_CNT);
    ull*   t_cnt   = cnts + 0;
    ull*   rp_cnt  = cnts + 1;
    ull*   r_done  = cnts + 2;
    const float* wvp = (const float*)(ws + WS_WVP);
    float* rp      = (float*)(ws + WS_RP);
    float* rv      = (float*)(ws + WS_RV);

    const int b    = blockIdx.x;
    const int tid  = threadIdx.x;
    const int lane = tid & 63;
    const int wid  = tid >> 6;       // 0..7
    const int c0   = lane * 4;
    const int c1   = 256 + lane * 4;

    __shared__ float lds[8][D_IN];
    __shared__ float t_lds[D_IN];
    __shared__ float rv_lds[D_IN];
    __shared__ float u_lds[8];
    __shared__ unsigned flag_s;

    // ---- issue this wave's 4 X rows into registers (HBM, exactly once)
    float4 xa[4], xb[4];
    const int row0 = b * 32 + wid * 4;
#pragma unroll
    for (int r = 0; r < 4; ++r) {
        const float* xr = X + (size_t)(row0 + r) * D_IN;
        xa[r] = *(const float4*)(xr + c0);
        xb[r] = *(const float4*)(xr + c1);
    }

    // ---- w_v: reduce 8 prep slices with PLAIN vectorized loads (cached;
    //      producer is the previous kernel -> visible by stream ordering)
    float4 wv0 = {0.f,0.f,0.f,0.f}, wv1 = {0.f,0.f,0.f,0.f};
#pragma unroll
    for (int j = 0; j < 8; ++j) {
        const float4 a = *(const float4*)(wvp + (size_t)j * D_IN + c0);
        const float4 bq = *(const float4*)(wvp + (size_t)j * D_IN + c1);
        wv0.x += a.x;  wv0.y += a.y;  wv0.z += a.z;  wv0.w += a.w;
        wv1.x += bq.x; wv1.y += bq.y; wv1.z += bq.z; wv1.w += bq.w;
    }

    // ---- phase 2: s_i dot + rank-1 t (from registers)
    float4 t0 = {0.f,0.f,0.f,0.f};
    float4 t1 = {0.f,0.f,0.f,0.f};
#pragma unroll
    for (int r = 0; r < 4; ++r) {
        float p = xa[r].x*wv0.x + xa[r].y*wv0.y + xa[r].z*wv0.z + xa[r].w*wv0.w
                + xb[r].x*wv1.x + xb[r].y*wv1.y + xb[r].z*wv1.z + xb[r].w*wv1.w;
#pragma unroll
        for (int off = 32; off >= 1; off >>= 1) p += __shfl_xor(p, off, 64);
        t0.x += p*xa[r].x; t0.y += p*xa[r].y; t0.z += p*xa[r].z; t0.w += p*xa[r].w;
        t1.x += p*xb[r].x; t1.y += p*xb[r].y; t1.z += p*xb[r].z; t1.w += p*xb[r].w;
    }
    *(float4*)(&lds[wid][c0]) = t0;
    *(float4*)(&lds[wid][c1]) = t1;
    __syncthreads();
    {
        float s = 0.f;
#pragma unroll
        for (int w = 0; w < 8; ++w) s += lds[w][tid];
        const long long v = llrintf(s * SCALE);
        ull old = atomicAdd(&t_fixed[(size_t)(b & 7) * D_IN + tid], (ull)v);
        unsigned keep = (unsigned)old ^ (unsigned)(old >> 32);
        asm volatile("" :: "v"(keep));   // RMW applied before barrier (R5 pattern)
    }
    __syncthreads();

    if (tid == 0) flag_s = (unsigned)atomicAdd(t_cnt, 1ull);
    __syncthreads();
    const unsigned arrival = flag_s;

    // ---- phase 3: last-32 arrivals compute u and rp slices (R5-verbatim)
    if (arrival >= 224u) {
        const int k = (int)arrival - 224;
        if (tid == 0) {
            while (atomicAdd(t_cnt, 0ull) < 256ull) __builtin_amdgcn_s_sleep(8);
        }
        __syncthreads();

        long long acc = 0;
#pragma unroll
        for (int j = 0; j < 8; ++j)
            acc += (long long)atomicAdd(&t_fixed[(size_t)j * D_IN + tid], 0ull);
        t_lds[tid] = (float)acc * INV_SCALE;
        __syncthreads();

        {   // u[e] for e = 8k + wid
            const int e = 8 * k + wid;
            const float4 ta = *(const float4*)(t_lds + c0);
            const float4 tb = *(const float4*)(t_lds + c1);
            const float4 ka = *(const float4*)(W_K + (size_t)e * D_IN + c0);
            const float4 kb = *(const float4*)(W_K + (size_t)e * D_IN + c1);
            float p = ta.x*ka.x + ta.y*ka.y + ta.z*ka.z + ta.w*ka.w
                    + tb.x*kb.x + tb.y*kb.y + tb.z*kb.z + tb.w*kb.w;
#pragma unroll
            for (int off = 32; off >= 1; off >>= 1) p += __shfl_xor(p, off, 64);
            if (lane == 0) u_lds[wid] = p;
        }
        __syncthreads();

        {   // rp[k][tid] = sum_m u[m] * W_Q[8k+m][tid]
            float racc = 0.f;
#pragma unroll
            for (int m = 0; m < 8; ++m)
                racc += u_lds[m] * W_Q[(size_t)(8 * k + m) * D_IN + tid];
            fstore_cg(&rp[(size_t)k * D_IN + tid], racc);
        }
        __syncthreads();                 // drains vmcnt -> rp at coherence point
        if (tid == 0) flag_s = ((unsigned)atomicAdd(rp_cnt, 1ull) == 31u) ? 1u : 0u;
        __syncthreads();

        if (flag_s) {                    // designated r reducer, fixed order
            float s = 0.f;
#pragma unroll 8
            for (int j = 0; j < 32; ++j) s += fload_cg(&rp[(size_t)j * D_IN + tid]);
            fstore_cg(&rv[tid], s);
            __syncthreads();             // drains vmcnt -> rv at coherence point
            if (tid == 0) atomicAdd(r_done, 1ull);
        }
    }

    // ---- phase 4: relaxed-poll r_done; stage rv through LDS ONCE per block
    if (tid == 0) {
        while (uload_cg(r_done) == 0ull) __builtin_amdgcn_s_sleep(4);
    }
    __syncthreads();

    if (tid < 256) {                     // 256 x 8-byte coherent loads per block
        ull two = uload_cg((const ull*)rv + tid);
        rv_lds[2 * tid]     = __builtin_bit_cast(float, (unsigned)two);
        rv_lds[2 * tid + 1] = __builtin_bit_cast(float, (unsigned)(two >> 32));
    }
    __syncthreads();

    const float4 r0 = *(const float4*)(rv_lds + c0);
    const float4 r1 = *(const float4*)(rv_lds + c1);
    const float bb = head_b[0];

#pragma unroll
    for (int r = 0; r < 4; ++r) {
        float p = xa[r].x*r0.x + xa[r].y*r0.y + xa[r].z*r0.z + xa[r].w*r0.w
                + xb[r].x*r1.x + xb[r].y*r1.y + xb[r].z*r1.z + xb[r].w*r1.w;
#pragma unroll
        for (int off = 32; off >= 1; off >>= 1) p += __shfl_xor(p, off, 64);
        if (lane == 0) out[row0 + r] = p + bb;
    }
}

// ---------------------------------------------------------------------------
extern "C" void kernel_launch(void* const* d_in, const int* in_sizes, int n_in,
                              void* d_out, int out_size, void* d_ws, size_t ws_size,
                              hipStream_t stream) {
    const float* X      = (const float*)d_in[0];
    const float* W_Q    = (const float*)d_in[1];
    const float* W_K    = (const float*)d_in[2];
    const float* W_V    = (const float*)d_in[3];
    const float* head_w = (const float*)d_in[4];
    const float* head_b = (const float*)d_in[5];
    float* out = (float*)d_out;
    char* ws   = (char*)d_ws;

    float* wvp = (float*)(ws + WS_WVP);

    k_prep  <<<8,    512, 0, stream>>>(W_V, head_w, wvp, (ull*)ws);
    k_fused2<<<NBLK, 512, 0, stream>>>(X, W_Q, W_K, head_b, out, ws);
}

// Round 9
// 26.255 us; speedup vs baseline: 2.9526x; 1.0335x over previous
//
#include <hip/hip_runtime.h>

typedef unsigned long long ull;

#define D_IN 512
#define NBLK 256
#define SCALE 16777216.0f
#define INV_SCALE 5.9604644775390625e-08f
#define AG __HIP_MEMORY_SCOPE_AGENT

// ws byte layout (regions 4KB-isolated so no line aliasing across roles):
//   t_fixed @ 0     : ull[8*512] (32 KB) fixed-point t, 8 copies
//   r_fixed @ 32768 : ull[512]   (4 KB)  fixed-point r accumulator
//   cnts    @ 36864 : ull[8]   (t_cnt, r_cnt)
//   wvp     @ 40960 : float[8*512] (16 KB) w_v slices
#define WS_TFX 0
#define WS_RFX 32768
#define WS_CNT 36864
#define WS_WVP 40960
#define N_ZERO 4616      // ulls: t_fixed(4096) + r_fixed(512) + cnts(8)

__device__ __forceinline__ void fstore_cg(float* p, float v) {
    __hip_atomic_store((unsigned*)p, __builtin_bit_cast(unsigned, v),
                       __ATOMIC_RELAXED, AG);
}
__device__ __forceinline__ ull uload_cg(const ull* p) {
    return __hip_atomic_load(p, __ATOMIC_RELAXED, AG);
}
// 16B load forced to the coherence point (same sc0+sc1 policy the compiler
// uses for agent atomic loads) — fresh data, vector width, no L1/L2 staleness.
__device__ __forceinline__ ulonglong2 load_b128_coherent(const ull* p) {
    ulonglong2 v;
    asm volatile("global_load_dwordx4 %0, %1, off sc0 sc1\n\t"
                 "s_waitcnt vmcnt(0)"
                 : "=&v"(v) : "v"(p) : "memory");
    return v;
}

// ---------------------------------------------------------------------------
// K0: wvp slices + zero protocol state (poison-proof; every call).
// Plain stores -> visible to K1's plain loads by stream ordering.
// ---------------------------------------------------------------------------
__global__ __launch_bounds__(512) void k_prep(const float* __restrict__ W_V,
                                              const float* __restrict__ head_w,
                                              float* __restrict__ wvp,
                                              ull* __restrict__ z) {
    const int j   = blockIdx.x;      // 0..7 -> e chunk [32j, 32j+32)
    const int tid = threadIdx.x;     // column
    float acc = 0.f;
    const int e0 = j * 32;
#pragma unroll 8
    for (int m = 0; m < 32; ++m)
        acc += head_w[e0 + m] * W_V[(size_t)(e0 + m) * D_IN + tid];
    wvp[(size_t)j * D_IN + tid] = acc;

    for (int i = j * 512 + tid; i < N_ZERO; i += 8 * 512) z[i] = 0ull;
}

// ---------------------------------------------------------------------------
// K1: single pass. 256 blocks x 512 threads (1 block/CU).
//   B: s_i = x_i.wv, rank-1 t -> LDS reduce -> int64 atomics (8 copies)
//   C: last-32 arrivals: t fan-in (atomic loads), u[8k..8k+8), r slice
//      accumulated DIRECTLY into r_fixed via int64 atomics (no serial reducer)
//   D: all blocks poll r_cnt==32, bypass-load r_fixed, re-dot L2-warm X.
// Deterministic: fixed-order reductions + commutative integer atomics.
// ---------------------------------------------------------------------------
__global__ __launch_bounds__(512) void k_one(
    const float* __restrict__ X,
    const float* __restrict__ W_Q,
    const float* __restrict__ W_K,
    const float* __restrict__ head_b,
    float* __restrict__ out,
    char* __restrict__ ws)
{
    ull*   t_fixed = (ull*)(ws + WS_TFX);
    ull*   r_fixed = (ull*)(ws + WS_RFX);
    ull*   cnts    = (ull*)(ws + WS_CNT);
    ull*   t_cnt   = cnts + 0;
    ull*   r_cnt   = cnts + 1;
    const float* wvp = (const float*)(ws + WS_WVP);

    const int b    = blockIdx.x;
    const int tid  = threadIdx.x;
    const int lane = tid & 63;
    const int wid  = tid >> 6;       // 0..7
    const int c0   = lane * 4;
    const int c1   = 256 + lane * 4;

    __shared__ float lds[8][D_IN];
    __shared__ float t_lds[D_IN];
    __shared__ float r_lds[D_IN];
    __shared__ float u_lds[8];
    __shared__ unsigned flag_s;

    // ---- w_v: reduce 8 prep slices with plain vectorized loads (cached;
    //      producer is the previous kernel -> stream-ordered visibility)
    float4 wv0 = {0.f,0.f,0.f,0.f}, wv1 = {0.f,0.f,0.f,0.f};
#pragma unroll
    for (int j = 0; j < 8; ++j) {
        const float4 a  = *(const float4*)(wvp + (size_t)j * D_IN + c0);
        const float4 bq = *(const float4*)(wvp + (size_t)j * D_IN + c1);
        wv0.x += a.x;  wv0.y += a.y;  wv0.z += a.z;  wv0.w += a.w;
        wv1.x += bq.x; wv1.y += bq.y; wv1.z += bq.z; wv1.w += bq.w;
    }

    // ---- phase B: stream 4 rows/wave: s_i dot + rank-1 t
    float4 t0 = {0.f,0.f,0.f,0.f};
    float4 t1 = {0.f,0.f,0.f,0.f};
    const int row0 = b * 32 + wid * 4;
#pragma unroll
    for (int r = 0; r < 4; ++r) {
        const float* xr = X + (size_t)(row0 + r) * D_IN;
        const float4 a  = *(const float4*)(xr + c0);
        const float4 bq = *(const float4*)(xr + c1);
        float p = a.x*wv0.x  + a.y*wv0.y  + a.z*wv0.z  + a.w*wv0.w
                + bq.x*wv1.x + bq.y*wv1.y + bq.z*wv1.z + bq.w*wv1.w;
#pragma unroll
        for (int off = 32; off >= 1; off >>= 1) p += __shfl_xor(p, off, 64);
        t0.x += p*a.x;  t0.y += p*a.y;  t0.z += p*a.z;  t0.w += p*a.w;
        t1.x += p*bq.x; t1.y += p*bq.y; t1.z += p*bq.z; t1.w += p*bq.w;
    }
    *(float4*)(&lds[wid][c0]) = t0;
    *(float4*)(&lds[wid][c1]) = t1;
    __syncthreads();
    {
        float s = 0.f;
#pragma unroll
        for (int w = 0; w < 8; ++w) s += lds[w][tid];
        const long long v = llrintf(s * SCALE);
        ull old = atomicAdd(&t_fixed[(size_t)(b & 7) * D_IN + tid], (ull)v);
        unsigned keep = (unsigned)old ^ (unsigned)(old >> 32);
        asm volatile("" :: "v"(keep));   // RMW applied before barrier (R5 pattern)
    }
    __syncthreads();

    if (tid == 0) flag_s = (unsigned)atomicAdd(t_cnt, 1ull);
    __syncthreads();
    const unsigned arrival = flag_s;

    // ---- phase C: last-32 arrivals: u slice + direct r_fixed accumulation
    if (arrival >= 224u) {
        const int k = (int)arrival - 224;
        if (tid == 0) {
            while (uload_cg(t_cnt) < 256ull) __builtin_amdgcn_s_sleep(1);
        }
        __syncthreads();

        long long acc = 0;
#pragma unroll
        for (int j = 0; j < 8; ++j)
            acc += (long long)uload_cg(&t_fixed[(size_t)j * D_IN + tid]);
        t_lds[tid] = (float)acc * INV_SCALE;
        __syncthreads();

        {   // u[e] for e = 8k + wid (wave dot, W_K row cached/coalesced)
            const int e = 8 * k + wid;
            const float4 ta = *(const float4*)(t_lds + c0);
            const float4 tb = *(const float4*)(t_lds + c1);
            const float4 ka = *(const float4*)(W_K + (size_t)e * D_IN + c0);
            const float4 kb = *(const float4*)(W_K + (size_t)e * D_IN + c1);
            float p = ta.x*ka.x + ta.y*ka.y + ta.z*ka.z + ta.w*ka.w
                    + tb.x*kb.x + tb.y*kb.y + tb.z*kb.z + tb.w*kb.w;
#pragma unroll
            for (int off = 32; off >= 1; off >>= 1) p += __shfl_xor(p, off, 64);
            if (lane == 0) u_lds[wid] = p;
        }
        __syncthreads();

        {   // r slice -> fixed-point atomic accumulate (no serial reducer)
            float racc = 0.f;
#pragma unroll
            for (int m = 0; m < 8; ++m)
                racc += u_lds[m] * W_Q[(size_t)(8 * k + m) * D_IN + tid];
            const long long v = llrintf(racc * SCALE);
            ull old = atomicAdd(&r_fixed[tid], (ull)v);
            unsigned keep = (unsigned)old ^ (unsigned)(old >> 32);
            asm volatile("" :: "v"(keep));
        }
        __syncthreads();                 // all 512 r-RMWs applied
        if (tid == 0) atomicAdd(r_cnt, 1ull);
    }

    // ---- phase D: poll r_cnt==32; bypass-load r_fixed; final dot (L2-warm X)
    if (tid == 0) {
        while (uload_cg(r_cnt) < 32ull) __builtin_amdgcn_s_sleep(2);
    }
    __syncthreads();

    if (tid < 256) {
        ulonglong2 v = load_b128_coherent(r_fixed + 2 * tid);
        r_lds[2 * tid]     = (float)(long long)v.x * INV_SCALE;
        r_lds[2 * tid + 1] = (float)(long long)v.y * INV_SCALE;
    }
    __syncthreads();

    const float4 r0 = *(const float4*)(r_lds + c0);
    const float4 r1 = *(const float4*)(r_lds + c1);
    const float bb  = head_b[0];

#pragma unroll
    for (int r = 0; r < 4; ++r) {
        const float* xr = X + (size_t)(row0 + r) * D_IN;
        const float4 a  = *(const float4*)(xr + c0);
        const float4 bq = *(const float4*)(xr + c1);
        float p = a.x*r0.x  + a.y*r0.y  + a.z*r0.z  + a.w*r0.w
                + bq.x*r1.x + bq.y*r1.y + bq.z*r1.z + bq.w*r1.w;
#pragma unroll
        for (int off = 32; off >= 1; off >>= 1) p += __shfl_xor(p, off, 64);
        if (lane == 0) out[row0 + r] = p + bb;
    }
}

// ---------------------------------------------------------------------------
extern "C" void kernel_launch(void* const* d_in, const int* in_sizes, int n_in,
                              void* d_out, int out_size, void* d_ws, size_t ws_size,
                              hipStream_t stream) {
    const float* X      = (const float*)d_in[0];
    const float* W_Q    = (const float*)d_in[1];
    const float* W_K    = (const float*)d_in[2];
    const float* W_V    = (const float*)d_in[3];
    const float* head_w = (const float*)d_in[4];
    const float* head_b = (const float*)d_in[5];
    float* out = (float*)d_out;
    char* ws   = (char*)d_ws;

    float* wvp = (float*)(ws + WS_WVP);

    k_prep<<<8,    512, 0, stream>>>(W_V, head_w, wvp, (ull*)ws);
    k_one <<<NBLK, 512, 0, stream>>>(X, W_Q, W_K, head_b, out, ws);
}

// Round 11
// 23.641 us; speedup vs baseline: 3.2790x; 1.1106x over previous
//
#include <hip/hip_runtime.h>

typedef unsigned long long ull;

#define D_IN 512
#define NBLK 256
#define NTAIL 32
#define SCALE 16777216.0f
#define INV_SCALE 5.9604644775390625e-08f
#define AG __HIP_MEMORY_SCOPE_AGENT

// keep a float4 pinned in VGPRs across the protocol wait (scalar constraints;
// tuple "+v"(float4) is unsupported on gfx950 — R10 compile failure)
#define KEEP4(v) asm volatile("" : "+v"(v.x), "+v"(v.y), "+v"(v.z), "+v"(v.w))

// ws byte layout:
//   t_fixed @ 0      : ull[8*512] (32 KB) fixed-point t, 8 copies     [zeroed]
//   r_fixed @ 32768  : ull[512]   (4 KB)  fixed-point r accumulator   [zeroed]
//   cnts    @ 36864  : ull[8]     (t_cnt, r_cnt)                      [zeroed]
//   rflag   @ 36928  : ull[32*8]  flag k at +k*64B (own line each)    [zeroed]
//   rrep    @ 40960  : float[32][512] (64 KB) r replicas   [fresh-written]
//   wvp     @ 106496 : float[8*512]   (16 KB) w_v slices   [fresh-written]
#define WS_TFX   0
#define WS_RFX   32768
#define WS_CNT   36864
#define WS_RFLAG 36928
#define WS_RREP  40960
#define WS_WVP   106496
#define N_ZERO   4872    // ulls: t_fixed 4096 + r_fixed 512 + cnts 8 + rflag 256

__device__ __forceinline__ void fstore_cg(float* p, float v) {
    __hip_atomic_store((unsigned*)p, __builtin_bit_cast(unsigned, v),
                       __ATOMIC_RELAXED, AG);
}
__device__ __forceinline__ ull uload_cg(const ull* p) {
    return __hip_atomic_load(p, __ATOMIC_RELAXED, AG);
}
// 16B load forced to the coherence point (sc0+sc1 = agent-atomic-load policy).
__device__ __forceinline__ ulonglong2 load_b128_coherent(const ull* p) {
    ulonglong2 v;
    asm volatile("global_load_dwordx4 %0, %1, off sc0 sc1\n\t"
                 "s_waitcnt vmcnt(0)"
                 : "=&v"(v) : "v"(p) : "memory");
    return v;
}

// ---------------------------------------------------------------------------
// K0: wvp slices + zero protocol state (poison-proof; every call).
// ---------------------------------------------------------------------------
__global__ __launch_bounds__(512) void k_prep(const float* __restrict__ W_V,
                                              const float* __restrict__ head_w,
                                              float* __restrict__ wvp,
                                              ull* __restrict__ z) {
    const int j   = blockIdx.x;      // 0..7 -> e chunk [32j, 32j+32)
    const int tid = threadIdx.x;     // column
    float acc = 0.f;
    const int e0 = j * 32;
#pragma unroll 8
    for (int m = 0; m < 32; ++m)
        acc += head_w[e0 + m] * W_V[(size_t)(e0 + m) * D_IN + tid];
    wvp[(size_t)j * D_IN + tid] = acc;

    for (int i = j * 512 + tid; i < N_ZERO; i += 8 * 512) z[i] = 0ull;
}

// ---------------------------------------------------------------------------
// K1: single pass. 256 blocks x 512 threads (1 block/CU, all co-resident).
//  A: w_v from prep slices (plain cached); prefetch W_K/W_Q slice into L2/L3.
//  B: X -> registers (read once); s_i dot; rank-1 t; int64 t atomics (8 copies).
//  C: last-32 arrivals: t fan-in, u[8k..8k+8), r slice -> r_fixed atomics;
//     after r_cnt==32 each tail writes a FULL r replica + its own flag line.
//  D: poller b waits flag[b&31], reads replica b&31 (8-way contention only);
//     final dot from the X still in registers.
// Deterministic: fixed-order reductions + commutative integer atomics.
// ---------------------------------------------------------------------------
__global__ __launch_bounds__(512) void k_one(
    const float* __restrict__ X,
    const float* __restrict__ W_Q,
    const float* __restrict__ W_K,
    const float* __restrict__ head_b,
    float* __restrict__ out,
    char* __restrict__ ws)
{
    ull*   t_fixed = (ull*)(ws + WS_TFX);
    ull*   r_fixed = (ull*)(ws + WS_RFX);
    ull*   cnts    = (ull*)(ws + WS_CNT);
    ull*   t_cnt   = cnts + 0;
    ull*   r_cnt   = cnts + 1;
    ull*   rflag   = (ull*)(ws + WS_RFLAG);   // flag k at rflag[k*8]
    float* rrep    = (float*)(ws + WS_RREP);  // [32][512]
    const float* wvp = (const float*)(ws + WS_WVP);

    const int b    = blockIdx.x;
    const int tid  = threadIdx.x;
    const int lane = tid & 63;
    const int wid  = tid >> 6;       // 0..7
    const int c0   = lane * 4;
    const int c1   = 256 + lane * 4;

    __shared__ float lds[8][D_IN];
    __shared__ float t_lds[D_IN];
    __shared__ float r_lds[D_IN];
    __shared__ float u_lds[8];
    __shared__ unsigned flag_s;

    // ---- phase A: prefetch this block's 2KB slice of W_K and W_Q (covers
    //      both matrices exactly across 256 blocks; cacheable -> L2/L3 warm
    //      for the tail). Sink via asm to avoid DCE.
    {
        float pk = W_K[(size_t)b * 512 + tid];
        float pq = W_Q[(size_t)b * 512 + tid];
        asm volatile("" :: "v"(pk), "v"(pq));
    }
    // ---- w_v: reduce 8 prep slices with plain vectorized loads
    float4 wv0 = {0.f,0.f,0.f,0.f}, wv1 = {0.f,0.f,0.f,0.f};
#pragma unroll
    for (int j = 0; j < 8; ++j) {
        const float4 a  = *(const float4*)(wvp + (size_t)j * D_IN + c0);
        const float4 bq = *(const float4*)(wvp + (size_t)j * D_IN + c1);
        wv0.x += a.x;  wv0.y += a.y;  wv0.z += a.z;  wv0.w += a.w;
        wv1.x += bq.x; wv1.y += bq.y; wv1.z += bq.z; wv1.w += bq.w;
    }

    // ---- phase B: X rows -> registers (HBM read, exactly once)
    float4 xa[4], xb[4];
    const int row0 = b * 32 + wid * 4;
#pragma unroll
    for (int r = 0; r < 4; ++r) {
        const float* xr = X + (size_t)(row0 + r) * D_IN;
        xa[r] = *(const float4*)(xr + c0);
        xb[r] = *(const float4*)(xr + c1);
    }

    float4 t0 = {0.f,0.f,0.f,0.f};
    float4 t1 = {0.f,0.f,0.f,0.f};
#pragma unroll
    for (int r = 0; r < 4; ++r) {
        float p = xa[r].x*wv0.x + xa[r].y*wv0.y + xa[r].z*wv0.z + xa[r].w*wv0.w
                + xb[r].x*wv1.x + xb[r].y*wv1.y + xb[r].z*wv1.z + xb[r].w*wv1.w;
#pragma unroll
        for (int off = 32; off >= 1; off >>= 1) p += __shfl_xor(p, off, 64);
        t0.x += p*xa[r].x; t0.y += p*xa[r].y; t0.z += p*xa[r].z; t0.w += p*xa[r].w;
        t1.x += p*xb[r].x; t1.y += p*xb[r].y; t1.z += p*xb[r].z; t1.w += p*xb[r].w;
    }
    *(float4*)(&lds[wid][c0]) = t0;
    *(float4*)(&lds[wid][c1]) = t1;
    __syncthreads();
    {
        float s = 0.f;
#pragma unroll
        for (int w = 0; w < 8; ++w) s += lds[w][tid];
        const long long v = llrintf(s * SCALE);
        ull old = atomicAdd(&t_fixed[(size_t)(b & 7) * D_IN + tid], (ull)v);
        unsigned keep = (unsigned)old ^ (unsigned)(old >> 32);
        asm volatile("" :: "v"(keep));   // RMW applied before barrier
    }
    __syncthreads();

    if (tid == 0) flag_s = (unsigned)atomicAdd(t_cnt, 1ull);
    __syncthreads();
    const unsigned arrival = flag_s;

    if (arrival >= (unsigned)(NBLK - NTAIL)) {
        // ---- phase C (block-uniform branch): tail work
        const int k = (int)arrival - (NBLK - NTAIL);
        if (tid == 0) {
            while (uload_cg(t_cnt) < (ull)NBLK) __builtin_amdgcn_s_sleep(4);
        }
        __syncthreads();

        long long acc = 0;
#pragma unroll
        for (int j = 0; j < 8; ++j)
            acc += (long long)uload_cg(&t_fixed[(size_t)j * D_IN + tid]);
        t_lds[tid] = (float)acc * INV_SCALE;
        __syncthreads();

        {   // u[e] for e = 8k + wid (W_K row L2/L3-warm from prefetch)
            const int e = 8 * k + wid;
            const float4 ta = *(const float4*)(t_lds + c0);
            const float4 tb = *(const float4*)(t_lds + c1);
            const float4 ka = *(const float4*)(W_K + (size_t)e * D_IN + c0);
            const float4 kb = *(const float4*)(W_K + (size_t)e * D_IN + c1);
            float p = ta.x*ka.x + ta.y*ka.y + ta.z*ka.z + ta.w*ka.w
                    + tb.x*kb.x + tb.y*kb.y + tb.z*kb.z + tb.w*kb.w;
#pragma unroll
            for (int off = 32; off >= 1; off >>= 1) p += __shfl_xor(p, off, 64);
            if (lane == 0) u_lds[wid] = p;
        }
        __syncthreads();

        {   // r slice -> fixed-point atomic accumulate
            float racc = 0.f;
#pragma unroll
            for (int m = 0; m < 8; ++m)
                racc += u_lds[m] * W_Q[(size_t)(8 * k + m) * D_IN + tid];
            const long long v = llrintf(racc * SCALE);
            ull old = atomicAdd(&r_fixed[tid], (ull)v);
            unsigned keep = (unsigned)old ^ (unsigned)(old >> 32);
            asm volatile("" :: "v"(keep));
        }
        __syncthreads();                 // all 512 r-RMWs applied
        if (tid == 0) atomicAdd(r_cnt, 1ull);

        // ---- wait for full r, then broadcast a replica on own flag line
        if (tid == 0) {
            while (uload_cg(r_cnt) < (ull)NTAIL) __builtin_amdgcn_s_sleep(1);
        }
        __syncthreads();
        {
            ull v = uload_cg(&r_fixed[tid]);
            float f = (float)(long long)v * INV_SCALE;
            r_lds[tid] = f;
            fstore_cg(&rrep[(size_t)k * D_IN + tid], f);
        }
        __syncthreads();                 // replica stores drained
        if (tid == 0) atomicAdd(&rflag[(size_t)k * 8], 1ull);
        __syncthreads();
    } else {
        // ---- phase D wait: poll own replica's flag (<=8 pollers per line)
        const int rep = b & 31;
        if (tid == 0) {
            while (uload_cg(&rflag[(size_t)rep * 8]) == 0ull)
                __builtin_amdgcn_s_sleep(2);
        }
        __syncthreads();
        if (tid < 128) {                 // 128 x 16B coherent loads per block
            ulonglong2 v = load_b128_coherent(
                (const ull*)(rrep + (size_t)rep * D_IN + tid * 4));
            r_lds[tid*4+0] = __builtin_bit_cast(float, (unsigned)v.x);
            r_lds[tid*4+1] = __builtin_bit_cast(float, (unsigned)(v.x >> 32));
            r_lds[tid*4+2] = __builtin_bit_cast(float, (unsigned)v.y);
            r_lds[tid*4+3] = __builtin_bit_cast(float, (unsigned)(v.y >> 32));
        }
        __syncthreads();
    }

    // ---- final dot from the X still in registers (no memory reads)
#pragma unroll
    for (int r = 0; r < 4; ++r) { KEEP4(xa[r]); KEEP4(xb[r]); }
    const float4 r0 = *(const float4*)(r_lds + c0);
    const float4 r1 = *(const float4*)(r_lds + c1);
    const float bb  = head_b[0];

#pragma unroll
    for (int r = 0; r < 4; ++r) {
        float p = xa[r].x*r0.x + xa[r].y*r0.y + xa[r].z*r0.z + xa[r].w*r0.w
                + xb[r].x*r1.x + xb[r].y*r1.y + xb[r].z*r1.z + xb[r].w*r1.w;
#pragma unroll
        for (int off = 32; off >= 1; off >>= 1) p += __shfl_xor(p, off, 64);
        if (lane == 0) out[row0 + r] = p + bb;
    }
}

// ---------------------------------------------------------------------------
extern "C" void kernel_launch(void* const* d_in, const int* in_sizes, int n_in,
                              void* d_out, int out_size, void* d_ws, size_t ws_size,
                              hipStream_t stream) {
    const float* X      = (const float*)d_in[0];
    const float* W_Q    = (const float*)d_in[1];
    const float* W_K    = (const float*)d_in[2];
    const float* W_V    = (const float*)d_in[3];
    const float* head_w = (const float*)d_in[4];
    const float* head_b = (const float*)d_in[5];
    float* out = (float*)d_out;
    char* ws   = (char*)d_ws;

    float* wvp = (float*)(ws + WS_WVP);

    k_prep<<<8,    512, 0, stream>>>(W_V, head_w, wvp, (ull*)ws);
    k_one <<<NBLK, 512, 0, stream>>>(X, W_Q, W_K, head_b, out, ws);
}